// Round 2
// baseline (2014.525 us; speedup 1.0000x reference)
//
#include <hip/hip_runtime.h>
#include <math.h>

// ConvAttention on MI355X — Round 2: fp32 baseline + workspace guard.
// B=8, Cin=64, Cout=128, L=18, H=W=32, heads=2.
// q = conv1x3x3(input)*0.5 ; k = conv1x3x3(memory) ; v = conv3x3x3(memory, no depth pad)
// logit[b,n,c,m] = sum_{d,h,w} q*k ; attn = softmax_m ; out = attn @ v, re-packed to (B,C,16,H,W).
//
// Workspace layout (floats), requires ws_size >= ~161 MiB:
//   q_ws   : 16*128*9216           (72 MiB)  -- reused for v after logits
//   k_ws   : 16*128*9216           (72 MiB)
//   part   : 16*16*128*128         (16 MiB)  split-K logit partials (deterministic, no atomics)
//   attn   : 16*128*128            ( 1 MiB)
// If ws_size is too small we launch NOTHING -> clean validation failure, not a crash.

#define B_     8
#define CIN    64
#define COUT   128
#define LDEPTH 18
#define HW2    1024   // 32*32
#define NH     2
#define DQ     9
#define PQ     9216   // DQ*1024
#define PV     8192   // 8*1024
#define CO_TILE 16
#define TS     35     // padded LDS row stride (odd -> spreads banks)
#define CH_STRIDE (34 * TS)   // 1190 floats per staged channel

// Stage 8 input channels of slice (b,l) into LDS with a zero border (34x34 padded).
__device__ __forceinline__ void stage_slice(float* xs, const float* __restrict__ X,
                                            int b, int l, int cin0, int tid) {
  const int total = 8 * 34 * 34;
  for (int idx = tid; idx < total; idx += 256) {
    const int ci = idx / 1156;
    const int r  = idx - ci * 1156;
    const int py = r / 34;
    const int px = r - py * 34;
    const int iy = py - 1, ix = px - 1;
    float v = 0.f;
    if (iy >= 0 && iy < 32 && ix >= 0 && ix < 32)
      v = X[(size_t)((b * CIN + cin0 + ci) * LDEPTH + l) * HW2 + iy * 32 + ix];
    xs[ci * CH_STRIDE + py * TS + px] = v;
  }
}

// ---------------- q / k conv: 1x3x3, spatial pad 1 ----------------
// grid (8 co-tiles, 144 slices), block 256. Thread: 16 co x 4 x-positions (one y row).
__global__ __launch_bounds__(256, 2) void conv_qk_kernel(
    const float* __restrict__ X, const float* __restrict__ W,
    const float* __restrict__ bias, float* __restrict__ out, float scale) {
  __shared__ float xs[8 * CH_STRIDE];
  const int tid = threadIdx.x;
  const int co0 = blockIdx.x * CO_TILE;
  const int s = blockIdx.y;               // b*18 + l
  const int b = s / LDEPTH;
  const int l = s - b * LDEPTH;
  const int n = (l >= DQ) ? 1 : 0;
  const int d = l - n * DQ;
  const int ty = tid >> 3;                // 0..31 output row
  const int x0 = (tid & 7) * 4;           // output col group

  float acc[CO_TILE][4];
#pragma unroll
  for (int i = 0; i < CO_TILE; ++i)
#pragma unroll
    for (int j = 0; j < 4; ++j) acc[i][j] = 0.f;

  for (int cc = 0; cc < 8; ++cc) {
    const int cin0 = cc * 8;
    __syncthreads();
    stage_slice(xs, X, b, l, cin0, tid);
    __syncthreads();
    for (int ci = 0; ci < 8; ++ci) {
      float xin[3][6];
#pragma unroll
      for (int ky = 0; ky < 3; ++ky)
#pragma unroll
        for (int e = 0; e < 6; ++e)
          xin[ky][e] = xs[ci * CH_STRIDE + (ty + ky) * TS + x0 + e];
      // weights are block-uniform -> scalar loads, FMA with SGPR operand
      const float* wp = W + ((size_t)co0 * CIN + cin0 + ci) * 9;
#pragma unroll
      for (int co = 0; co < CO_TILE; ++co) {
        const float* w = wp + (size_t)co * CIN * 9;
#pragma unroll
        for (int ky = 0; ky < 3; ++ky)
#pragma unroll
          for (int kx = 0; kx < 3; ++kx) {
            const float wv = w[ky * 3 + kx];
#pragma unroll
            for (int j = 0; j < 4; ++j)
              acc[co][j] = fmaf(wv, xin[ky][j + kx], acc[co][j]);
          }
      }
    }
  }
  // layout: q[((b*2+n)*128 + co)*9216 + d*1024 + y*32 + x]
  const size_t base = ((size_t)(b * NH + n) * COUT + co0) * PQ + d * HW2 + ty * 32 + x0;
#pragma unroll
  for (int co = 0; co < CO_TILE; ++co) {
    float4 o;
    o.x = (acc[co][0] + bias[co0 + co]) * scale;
    o.y = (acc[co][1] + bias[co0 + co]) * scale;
    o.z = (acc[co][2] + bias[co0 + co]) * scale;
    o.w = (acc[co][3] + bias[co0 + co]) * scale;
    *(float4*)(out + base + (size_t)co * PQ) = o;
  }
}

// ---------------- v conv: 3x3x3, depth pad 0, spatial pad 1 ----------------
// grid (8 co-tiles, 128 slices = B*16 output depths), block 256.
__global__ __launch_bounds__(256, 2) void conv_v_kernel(
    const float* __restrict__ X, const float* __restrict__ W,
    const float* __restrict__ bias, float* __restrict__ out) {
  __shared__ float xs[8 * CH_STRIDE];
  const int tid = threadIdx.x;
  const int co0 = blockIdx.x * CO_TILE;
  const int s = blockIdx.y;               // b*16 + dv
  const int b = s >> 4;
  const int dv = s & 15;
  const int n = dv >> 3;
  const int d = dv & 7;
  const int ty = tid >> 3;
  const int x0 = (tid & 7) * 4;

  float acc[CO_TILE][4];
#pragma unroll
  for (int i = 0; i < CO_TILE; ++i)
#pragma unroll
    for (int j = 0; j < 4; ++j) acc[i][j] = 0.f;

  for (int cc = 0; cc < 8; ++cc) {
    const int cin0 = cc * 8;
    for (int kd = 0; kd < 3; ++kd) {
      __syncthreads();
      stage_slice(xs, X, b, dv + kd, cin0, tid);
      __syncthreads();
      for (int ci = 0; ci < 8; ++ci) {
        float xin[3][6];
#pragma unroll
        for (int ky = 0; ky < 3; ++ky)
#pragma unroll
          for (int e = 0; e < 6; ++e)
            xin[ky][e] = xs[ci * CH_STRIDE + (ty + ky) * TS + x0 + e];
        const float* wp = W + ((size_t)co0 * CIN + cin0 + ci) * 27 + kd * 9;
#pragma unroll
        for (int co = 0; co < CO_TILE; ++co) {
          const float* w = wp + (size_t)co * CIN * 27;
#pragma unroll
          for (int ky = 0; ky < 3; ++ky)
#pragma unroll
            for (int kx = 0; kx < 3; ++kx) {
              const float wv = w[ky * 3 + kx];
#pragma unroll
              for (int j = 0; j < 4; ++j)
                acc[co][j] = fmaf(wv, xin[ky][j + kx], acc[co][j]);
            }
        }
      }
    }
  }
  // layout: v[((b*2+n)*128 + co)*8192 + d*1024 + y*32 + x]
  const size_t base = ((size_t)(b * NH + n) * COUT + co0) * PV + d * HW2 + ty * 32 + x0;
#pragma unroll
  for (int co = 0; co < CO_TILE; ++co) {
    float4 o;
    o.x = acc[co][0] + bias[co0 + co];
    o.y = acc[co][1] + bias[co0 + co];
    o.z = acc[co][2] + bias[co0 + co];
    o.w = acc[co][3] + bias[co0 + co];
    *(float4*)(out + base + (size_t)co * PV) = o;
  }
}

// ---------------- logits: split-K GEMM 128x128 over K=9216 ----------------
// grid (16 ksplit, 16 bn), block 256 (16x16 threads, 8x8 per thread). Deterministic partials.
__global__ __launch_bounds__(256, 2) void logit_kernel(
    const float* __restrict__ Qg, const float* __restrict__ Kg,
    float* __restrict__ part) {
  __shared__ float Qs[16][128];
  __shared__ float Ks[16][128];
  const int ks = blockIdx.x;
  const int bn = blockIdx.y;
  const float* Q = Qg + (size_t)bn * COUT * PQ;
  const float* K = Kg + (size_t)bn * COUT * PQ;
  const int tid = threadIdx.x;
  const int tc = tid >> 4;     // 0..15 (c block)
  const int tm = tid & 15;     // 0..15 (m lane, strided)
  float acc[8][8];
#pragma unroll
  for (int i = 0; i < 8; ++i)
#pragma unroll
    for (int j = 0; j < 8; ++j) acc[i][j] = 0.f;

  const int kbase = ks * 576;
  for (int kt = 0; kt < 36; ++kt) {
    const int k0 = kbase + kt * 16;
    __syncthreads();
#pragma unroll
    for (int i = 0; i < 2; ++i) {
      const int fid = tid + 256 * i;
      const int c = fid >> 2;
      const int kq = fid & 3;
      const float4 qa = *(const float4*)(Q + (size_t)c * PQ + k0 + kq * 4);
      const float4 ka = *(const float4*)(K + (size_t)c * PQ + k0 + kq * 4);
      Qs[kq * 4 + 0][c] = qa.x; Qs[kq * 4 + 1][c] = qa.y;
      Qs[kq * 4 + 2][c] = qa.z; Qs[kq * 4 + 3][c] = qa.w;
      Ks[kq * 4 + 0][c] = ka.x; Ks[kq * 4 + 1][c] = ka.y;
      Ks[kq * 4 + 2][c] = ka.z; Ks[kq * 4 + 3][c] = ka.w;
    }
    __syncthreads();
#pragma unroll
    for (int kk = 0; kk < 16; ++kk) {
      float a[8], bv[8];
      *(float4*)&a[0] = *(const float4*)&Qs[kk][tc * 8];
      *(float4*)&a[4] = *(const float4*)&Qs[kk][tc * 8 + 4];
#pragma unroll
      for (int j = 0; j < 8; ++j) bv[j] = Ks[kk][tm + 16 * j];  // stride-16 -> conflict-free
#pragma unroll
      for (int i = 0; i < 8; ++i)
#pragma unroll
        for (int j = 0; j < 8; ++j)
          acc[i][j] = fmaf(a[i], bv[j], acc[i][j]);
    }
  }
  float* pp = part + ((size_t)(bn * 16 + ks) << 14);
#pragma unroll
  for (int i = 0; i < 8; ++i)
#pragma unroll
    for (int j = 0; j < 8; ++j)
      pp[(tc * 8 + i) * 128 + tm + 16 * j] = acc[i][j];
}

// ---------------- reduce partials + row softmax ----------------
// grid 2048 (= 16 bn * 128 c rows), block 64 (one wave), 2 m-values per lane.
__global__ void softmax_kernel(const float* __restrict__ part, float* __restrict__ attn) {
  const int row = blockIdx.x;
  const int bn = row >> 7;
  const int c = row & 127;
  const int lane = threadIdx.x;
  float v0 = 0.f, v1 = 0.f;
  for (int ks = 0; ks < 16; ++ks) {
    const float* pp = part + ((size_t)(bn * 16 + ks) << 14) + c * 128;
    v0 += pp[lane];
    v1 += pp[lane + 64];
  }
  float mx = fmaxf(v0, v1);
#pragma unroll
  for (int off = 32; off > 0; off >>= 1) mx = fmaxf(mx, __shfl_xor(mx, off));
  const float e0 = expf(v0 - mx);
  const float e1 = expf(v1 - mx);
  float sum = e0 + e1;
#pragma unroll
  for (int off = 32; off > 0; off >>= 1) sum += __shfl_xor(sum, off);
  const float inv = 1.f / sum;
  float* rp = attn + ((size_t)bn << 14) + c * 128;
  rp[lane] = e0 * inv;
  rp[lane + 64] = e1 * inv;
}

// ---------------- out = attn @ v, packed to (B,C,16,H,W) ----------------
// grid (16 pos-tiles of 512, 2 c-tiles of 64, 16 bn), block 256 (8x32 threads, 8c x 16pos each).
__global__ __launch_bounds__(256, 2) void attnv_kernel(
    const float* __restrict__ attn, const float* __restrict__ Vg,
    float* __restrict__ out) {
  __shared__ float As[16][64];
  __shared__ float Vs[16][512];
  const int bn = blockIdx.z;
  const int b = bn >> 1, n = bn & 1;
  const int c0 = blockIdx.y * 64;
  const int p0 = blockIdx.x * 512;
  const int tid = threadIdx.x;
  const int tc = tid >> 5;     // 0..7
  const int tp = tid & 31;     // 0..31
  const float* V = Vg + (size_t)bn * COUT * PV;
  const float* A = attn + ((size_t)bn << 14);
  float acc[8][16];
#pragma unroll
  for (int i = 0; i < 8; ++i)
#pragma unroll
    for (int j = 0; j < 16; ++j) acc[i][j] = 0.f;

  for (int mt = 0; mt < 8; ++mt) {
    const int m0 = mt * 16;
    __syncthreads();
    {
      const int cc = tid >> 2, mq = tid & 3;
      const float4 aa = *(const float4*)(A + (size_t)(c0 + cc) * 128 + m0 + mq * 4);
      As[mq * 4 + 0][cc] = aa.x; As[mq * 4 + 1][cc] = aa.y;
      As[mq * 4 + 2][cc] = aa.z; As[mq * 4 + 3][cc] = aa.w;
#pragma unroll
      for (int i = 0; i < 8; ++i) {
        const int fid = tid + 256 * i;
        const int mm = fid >> 7, pq = fid & 127;
        const float4 vv = *(const float4*)(V + (size_t)(m0 + mm) * PV + p0 + pq * 4);
        *(float4*)&Vs[mm][pq * 4] = vv;
      }
    }
    __syncthreads();
#pragma unroll
    for (int mm = 0; mm < 16; ++mm) {
      float a[8];
      *(float4*)&a[0] = *(const float4*)&As[mm][tc * 8];
      *(float4*)&a[4] = *(const float4*)&As[mm][tc * 8 + 4];
#pragma unroll
      for (int j = 0; j < 16; ++j) {
        const float vv = Vs[mm][tp + 32 * j];   // stride-32 -> conflict-free
#pragma unroll
        for (int i = 0; i < 8; ++i)
          acc[i][j] = fmaf(a[i], vv, acc[i][j]);
      }
    }
  }
  // out[(b*128+c)*16384 + n*8192 + pos]
#pragma unroll
  for (int i = 0; i < 8; ++i) {
    const size_t ob = ((size_t)(b * COUT + c0 + tc * 8 + i) << 14) + ((size_t)n << 13) + p0 + tp;
#pragma unroll
    for (int j = 0; j < 16; ++j)
      out[ob + 32 * j] = acc[i][j];
  }
}

extern "C" void kernel_launch(void* const* d_in, const int* in_sizes, int n_in,
                              void* d_out, int out_size, void* d_ws, size_t ws_size,
                              hipStream_t stream) {
  const float* input  = (const float*)d_in[0];
  const float* memory = (const float*)d_in[1];
  const float* wq = (const float*)d_in[2];
  const float* bq = (const float*)d_in[3];
  const float* wk = (const float*)d_in[4];
  const float* bk = (const float*)d_in[5];
  const float* wv = (const float*)d_in[6];
  const float* bv = (const float*)d_in[7];
  float* out = (float*)d_out;

  const size_t QK_ELEMS = (size_t)16 * COUT * PQ;   // 18,874,368 floats (72 MiB)
  const size_t NEED_BYTES = (2 * QK_ELEMS + ((size_t)256 << 14) + ((size_t)16 << 14)) * 4;
  if (ws_size < NEED_BYTES) return;  // undersized workspace -> clean validation failure, not a crash

  float* q_ws = (float*)d_ws;
  float* k_ws = q_ws + QK_ELEMS;
  float* part = k_ws + QK_ELEMS;                    // 16*16*128*128 floats (16 MiB)
  float* attn = part + ((size_t)256 << 14);
  float* v_ws = q_ws;  // q region reused for v after logits (stream-ordered)

  conv_qk_kernel<<<dim3(8, 144), 256, 0, stream>>>(input, wq, bq, q_ws, 0.5f);
  conv_qk_kernel<<<dim3(8, 144), 256, 0, stream>>>(memory, wk, bk, k_ws, 1.0f);
  logit_kernel<<<dim3(16, 16), 256, 0, stream>>>(q_ws, k_ws, part);
  softmax_kernel<<<2048, 64, 0, stream>>>(part, attn);
  conv_v_kernel<<<dim3(8, 128), 256, 0, stream>>>(memory, wv, bv, v_ws);
  attnv_kernel<<<dim3(16, 2, 16), 256, 0, stream>>>(attn, v_ws, out);
}

// Round 5
// 843.560 us; speedup vs baseline: 2.3881x; 2.3881x over previous
//
#include <hip/hip_runtime.h>
#include <math.h>

// ConvAttention on MI355X — Round 5: fix conv_mfma<3> call (missing scale arg).
// Convs via bf16x3-split MFMA (16x16x32). B=8, Cin=64, Cout=128, L=18, H=W=32, heads=2.
// q = conv1x3x3(input)*0.5 ; k = conv1x3x3(memory) ; v = conv3x3x3(memory, no depth pad)
// logit/softmax/attnv unchanged from round-2 (known-passing).
//
// bf16x3: a = ah + al (two bf16), product ~ ah*bh + ah*bl + al*bh (drop al*bl, rel err ~2^-18).
// Conv-as-GEMM per slice: D[pos][co] = sum_k X_im2col[pos][k] * W[k][co].
//   A-frag (X): lane holds A[pos = l&15][k = (l>>4)*8 + j] -> ds_read_b128 from channel-last LDS.
//   B-frag (W): lane holds B[k][co = l&15] -> 16B global loads from repacked [co][tap][ci] planes.
//   D: col = lane&15 = co, row = (lane>>4)*4+reg = pos  (m89-verified) -> float4 stores.
//
// Workspace identical to round-2 (161 MiB): packed weights live in regions that are
// dead at the time they're needed (wq/wk in `part` pre-logit; wv in q-tail post-logit).

#define B_     8
#define CIN    64
#define COUT   128
#define LDEPTH 18
#define HW2    1024
#define NH     2
#define DQ     9
#define PQ     9216
#define PV     8192

typedef __attribute__((ext_vector_type(8))) short short8;
typedef __attribute__((ext_vector_type(4))) float f32x4;

static __device__ __forceinline__ unsigned short f2bf(float f) {
  unsigned u = __float_as_uint(f);
  unsigned r = (u + 0x7fffu + ((u >> 16) & 1u)) >> 16;   // RN-even
  return (unsigned short)r;
}
static __device__ __forceinline__ float bf2f(unsigned short h) {
  return __uint_as_float(((unsigned)h) << 16);
}

// ---------------- weight repack: [co][ci][taps] fp32 -> [co][tap][ci] bf16 hi/lo ----------------
__global__ void repack_w(const float* __restrict__ src, short* __restrict__ dh,
                         short* __restrict__ dl, int taps) {
  const int idx = blockIdx.x * 256 + threadIdx.x;
  const int total = 128 * 64 * taps;
  if (idx >= total) return;
  const int ci = idx & 63;
  const int t = idx >> 6;            // co*taps + tap
  const int co = t / taps;
  const int tap = t - co * taps;
  const float v = src[(size_t)(co * 64 + ci) * taps + tap];
  const unsigned short h = f2bf(v);
  dh[idx] = (short)h;
  dl[idx] = (short)f2bf(v - bf2f(h));
}

// Stage rows y0-1..y0+2 of slice (b,l), channels [ci0, ci0+32), into channel-last hi/lo LDS.
// LDS layout: elem[(row*34 + px)*40 + ci], padded stride 40 (bank-friendly).
__device__ __forceinline__ void stage_chunk(short* xh, short* xl, const float* __restrict__ X,
                                            int b, int l, int ci0, int y0, int tid) {
  for (int idx = tid; idx < 4352; idx += 256) {   // 32 ci * 4 rows * 34 px
    const int ci = idx / 136;
    const int r = idx - ci * 136;
    const int row = r / 34;
    const int px = r - row * 34;
    const int y = y0 - 1 + row;
    const int x = px - 1;
    float v = 0.f;
    if (y >= 0 && y < 32 && (unsigned)x < 32u)
      v = X[((size_t)(b * CIN + ci0 + ci) * LDEPTH + l) * HW2 + y * 32 + x];
    const unsigned short h = f2bf(v);
    const int cell = row * 34 + px;
    xh[cell * 40 + ci] = (short)h;
    xl[cell * 40 + ci] = (short)f2bf(v - bf2f(h));
  }
}

// ---------------- MFMA conv: block = 64 pos x 128 co, 4 waves (each 64 pos x 32 co) ----------------
template <int KD>
__global__ __launch_bounds__(256, 2) void conv_mfma(
    const float* __restrict__ X, const short* __restrict__ wh, const short* __restrict__ wl,
    const float* __restrict__ bias, float* __restrict__ out, float scale) {
  constexpr int TAPS = KD * 9;
  constexpr int OUTP = (KD == 1) ? PQ : PV;
  __shared__ __align__(16) short xh[4 * 34 * 40];
  __shared__ __align__(16) short xl[4 * 34 * 40];
  const int tid = threadIdx.x;
  const int wave = tid >> 6;
  const int lane = tid & 63;
  const int l15 = lane & 15;
  const int l4 = lane >> 4;

  const int s = blockIdx.y;
  int b, n, d, l_base;
  if (KD == 1) { b = s / LDEPTH; const int l = s - b * LDEPTH; n = (l >= DQ) ? 1 : 0; d = l - n * DQ; l_base = l; }
  else         { b = s >> 4; const int dv = s & 15; n = dv >> 3; d = dv & 7; l_base = dv; }
  const int p0 = blockIdx.x * 64;
  const int y0 = blockIdx.x * 2;

  f32x4 acc[2][4];
#pragma unroll
  for (int i = 0; i < 2; ++i)
#pragma unroll
    for (int j = 0; j < 4; ++j) acc[i][j] = (f32x4){0.f, 0.f, 0.f, 0.f};

  float bval[2];
  bval[0] = bias[wave * 32 + l15];
  bval[1] = bias[wave * 32 + 16 + l15];

  const short* ah_base = xh + l15 * 40 + l4 * 8;
  const short* al_base = xl + l15 * 40 + l4 * 8;

  for (int kd = 0; kd < KD; ++kd) {
    for (int cc = 0; cc < 2; ++cc) {
      __syncthreads();
      stage_chunk(xh, xl, X, b, l_base + kd, cc * 32, y0, tid);
      __syncthreads();
#pragma unroll
      for (int tap = 0; tap < 9; ++tap) {
        const int ky = tap / 3, kx = tap % 3;
        const int tapf = kd * 9 + tap;
        short8 bh[2], bl[2];
#pragma unroll
        for (int cf = 0; cf < 2; ++cf) {
          const size_t wofs = ((size_t)(wave * 32 + cf * 16 + l15) * TAPS + tapf) * 64 + cc * 32 + l4 * 8;
          bh[cf] = *(const short8*)(wh + wofs);
          bl[cf] = *(const short8*)(wl + wofs);
        }
        short8 ah[4], al[4];
#pragma unroll
        for (int pf = 0; pf < 4; ++pf) {
          const int off = (((pf >> 1) + ky) * 34 + (pf & 1) * 16 + kx) * 40;
          ah[pf] = *(const short8*)(ah_base + off);
          al[pf] = *(const short8*)(al_base + off);
        }
#pragma unroll
        for (int cf = 0; cf < 2; ++cf)
#pragma unroll
          for (int pf = 0; pf < 4; ++pf) {
            acc[cf][pf] = __builtin_amdgcn_mfma_f32_16x16x32_bf16(ah[pf], bh[cf], acc[cf][pf], 0, 0, 0);
            acc[cf][pf] = __builtin_amdgcn_mfma_f32_16x16x32_bf16(ah[pf], bl[cf], acc[cf][pf], 0, 0, 0);
            acc[cf][pf] = __builtin_amdgcn_mfma_f32_16x16x32_bf16(al[pf], bh[cf], acc[cf][pf], 0, 0, 0);
          }
      }
    }
  }

  const size_t obase = (size_t)((b * NH + n) * COUT) * OUTP + (size_t)d * HW2;
#pragma unroll
  for (int cf = 0; cf < 2; ++cf) {
    const int co = wave * 32 + cf * 16 + l15;
#pragma unroll
    for (int pf = 0; pf < 4; ++pf) {
      f32x4 r;
#pragma unroll
      for (int j = 0; j < 4; ++j) r[j] = (acc[cf][pf][j] + bval[cf]) * scale;
      const int pos = p0 + (pf >> 1) * 32 + (pf & 1) * 16 + l4 * 4;
      *(f32x4*)(out + obase + (size_t)co * OUTP + pos) = r;
    }
  }
}

// ---------------- logits: split-K GEMM 128x128 over K=9216 (unchanged) ----------------
__global__ __launch_bounds__(256, 2) void logit_kernel(
    const float* __restrict__ Qg, const float* __restrict__ Kg,
    float* __restrict__ part) {
  __shared__ float Qs[16][128];
  __shared__ float Ks[16][128];
  const int ks = blockIdx.x;
  const int bn = blockIdx.y;
  const float* Q = Qg + (size_t)bn * COUT * PQ;
  const float* K = Kg + (size_t)bn * COUT * PQ;
  const int tid = threadIdx.x;
  const int tc = tid >> 4;
  const int tm = tid & 15;
  float acc[8][8];
#pragma unroll
  for (int i = 0; i < 8; ++i)
#pragma unroll
    for (int j = 0; j < 8; ++j) acc[i][j] = 0.f;

  const int kbase = ks * 576;
  for (int kt = 0; kt < 36; ++kt) {
    const int k0 = kbase + kt * 16;
    __syncthreads();
#pragma unroll
    for (int i = 0; i < 2; ++i) {
      const int fid = tid + 256 * i;
      const int c = fid >> 2;
      const int kq = fid & 3;
      const float4 qa = *(const float4*)(Q + (size_t)c * PQ + k0 + kq * 4);
      const float4 ka = *(const float4*)(K + (size_t)c * PQ + k0 + kq * 4);
      Qs[kq * 4 + 0][c] = qa.x; Qs[kq * 4 + 1][c] = qa.y;
      Qs[kq * 4 + 2][c] = qa.z; Qs[kq * 4 + 3][c] = qa.w;
      Ks[kq * 4 + 0][c] = ka.x; Ks[kq * 4 + 1][c] = ka.y;
      Ks[kq * 4 + 2][c] = ka.z; Ks[kq * 4 + 3][c] = ka.w;
    }
    __syncthreads();
#pragma unroll
    for (int kk = 0; kk < 16; ++kk) {
      float a[8], bv[8];
      *(float4*)&a[0] = *(const float4*)&Qs[kk][tc * 8];
      *(float4*)&a[4] = *(const float4*)&Qs[kk][tc * 8 + 4];
#pragma unroll
      for (int j = 0; j < 8; ++j) bv[j] = Ks[kk][tm + 16 * j];
#pragma unroll
      for (int i = 0; i < 8; ++i)
#pragma unroll
        for (int j = 0; j < 8; ++j)
          acc[i][j] = fmaf(a[i], bv[j], acc[i][j]);
    }
  }
  float* pp = part + ((size_t)(bn * 16 + ks) << 14);
#pragma unroll
  for (int i = 0; i < 8; ++i)
#pragma unroll
    for (int j = 0; j < 8; ++j)
      pp[(tc * 8 + i) * 128 + tm + 16 * j] = acc[i][j];
}

// ---------------- reduce partials + row softmax (unchanged) ----------------
__global__ void softmax_kernel(const float* __restrict__ part, float* __restrict__ attn) {
  const int row = blockIdx.x;
  const int bn = row >> 7;
  const int c = row & 127;
  const int lane = threadIdx.x;
  float v0 = 0.f, v1 = 0.f;
  for (int ks = 0; ks < 16; ++ks) {
    const float* pp = part + ((size_t)(bn * 16 + ks) << 14) + c * 128;
    v0 += pp[lane];
    v1 += pp[lane + 64];
  }
  float mx = fmaxf(v0, v1);
#pragma unroll
  for (int off = 32; off > 0; off >>= 1) mx = fmaxf(mx, __shfl_xor(mx, off));
  const float e0 = expf(v0 - mx);
  const float e1 = expf(v1 - mx);
  float sum = e0 + e1;
#pragma unroll
  for (int off = 32; off > 0; off >>= 1) sum += __shfl_xor(sum, off);
  const float inv = 1.f / sum;
  float* rp = attn + ((size_t)bn << 14) + c * 128;
  rp[lane] = e0 * inv;
  rp[lane + 64] = e1 * inv;
}

// ---------------- out = attn @ v, packed to (B,C,16,H,W) (unchanged) ----------------
__global__ __launch_bounds__(256, 2) void attnv_kernel(
    const float* __restrict__ attn, const float* __restrict__ Vg,
    float* __restrict__ out) {
  __shared__ float As[16][64];
  __shared__ float Vs[16][512];
  const int bn = blockIdx.z;
  const int b = bn >> 1, n = bn & 1;
  const int c0 = blockIdx.y * 64;
  const int p0 = blockIdx.x * 512;
  const int tid = threadIdx.x;
  const int tc = tid >> 5;
  const int tp = tid & 31;
  const float* V = Vg + (size_t)bn * COUT * PV;
  const float* A = attn + ((size_t)bn << 14);
  float acc[8][16];
#pragma unroll
  for (int i = 0; i < 8; ++i)
#pragma unroll
    for (int j = 0; j < 16; ++j) acc[i][j] = 0.f;

  for (int mt = 0; mt < 8; ++mt) {
    const int m0 = mt * 16;
    __syncthreads();
    {
      const int cc = tid >> 2, mq = tid & 3;
      const float4 aa = *(const float4*)(A + (size_t)(c0 + cc) * 128 + m0 + mq * 4);
      As[mq * 4 + 0][cc] = aa.x; As[mq * 4 + 1][cc] = aa.y;
      As[mq * 4 + 2][cc] = aa.z; As[mq * 4 + 3][cc] = aa.w;
#pragma unroll
      for (int i = 0; i < 8; ++i) {
        const int fid = tid + 256 * i;
        const int mm = fid >> 7, pq = fid & 127;
        const float4 vv = *(const float4*)(V + (size_t)(m0 + mm) * PV + p0 + pq * 4);
        *(float4*)&Vs[mm][pq * 4] = vv;
      }
    }
    __syncthreads();
#pragma unroll
    for (int mm = 0; mm < 16; ++mm) {
      float a[8];
      *(float4*)&a[0] = *(const float4*)&As[mm][tc * 8];
      *(float4*)&a[4] = *(const float4*)&As[mm][tc * 8 + 4];
#pragma unroll
      for (int j = 0; j < 16; ++j) {
        const float vv = Vs[mm][tp + 32 * j];
#pragma unroll
        for (int i = 0; i < 8; ++i)
          acc[i][j] = fmaf(a[i], vv, acc[i][j]);
      }
    }
  }
#pragma unroll
  for (int i = 0; i < 8; ++i) {
    const size_t ob = ((size_t)(b * COUT + c0 + tc * 8 + i) << 14) + ((size_t)n << 13) + p0 + tp;
#pragma unroll
    for (int j = 0; j < 16; ++j)
      out[ob + 32 * j] = acc[i][j];
  }
}

extern "C" void kernel_launch(void* const* d_in, const int* in_sizes, int n_in,
                              void* d_out, int out_size, void* d_ws, size_t ws_size,
                              hipStream_t stream) {
  const float* input  = (const float*)d_in[0];
  const float* memory = (const float*)d_in[1];
  const float* wq = (const float*)d_in[2];
  const float* bq = (const float*)d_in[3];
  const float* wk = (const float*)d_in[4];
  const float* bk = (const float*)d_in[5];
  const float* wv = (const float*)d_in[6];
  const float* bv = (const float*)d_in[7];
  float* out = (float*)d_out;

  const size_t QK_ELEMS = (size_t)16 * COUT * PQ;   // 18,874,368 floats (72 MiB)
  const size_t NEED_BYTES = (2 * QK_ELEMS + ((size_t)256 << 14) + ((size_t)16 << 14)) * 4;
  if (ws_size < NEED_BYTES) return;  // clean validation failure, not a crash

  float* q_ws = (float*)d_ws;
  float* k_ws = q_ws + QK_ELEMS;
  float* part = k_ws + QK_ELEMS;                    // 16 MiB, written by logit AFTER convs
  float* attn = part + ((size_t)256 << 14);
  float* v_ws = q_ws;                               // q region reused for v after logits

  // Packed weights in dead regions:
  //  - wq/wk planes in `part` (logit overwrites it only after conv q/k consumed them)
  //  - wv planes in the q-tail [16*128*8192, 16*128*9216) (dead after logit; v uses only 8192/co)
  short* wpq_h = (short*)part;
  short* wpq_l = wpq_h + 128 * 9 * 64;
  short* wpk_h = wpq_l + 128 * 9 * 64;
  short* wpk_l = wpk_h + 128 * 9 * 64;
  short* wpv_h = (short*)(q_ws + (size_t)16 * COUT * PV);
  short* wpv_l = wpv_h + 128 * 27 * 64;

  repack_w<<<288, 256, 0, stream>>>(wq, wpq_h, wpq_l, 9);
  repack_w<<<288, 256, 0, stream>>>(wk, wpk_h, wpk_l, 9);
  conv_mfma<1><<<dim3(16, 144), 256, 0, stream>>>(input,  wpq_h, wpq_l, bq, q_ws, 0.5f);
  conv_mfma<1><<<dim3(16, 144), 256, 0, stream>>>(memory, wpk_h, wpk_l, bk, k_ws, 1.0f);
  logit_kernel<<<dim3(16, 16), 256, 0, stream>>>(q_ws, k_ws, part);
  softmax_kernel<<<2048, 64, 0, stream>>>(part, attn);
  repack_w<<<864, 256, 0, stream>>>(wv, wpv_h, wpv_l, 27);
  conv_mfma<3><<<dim3(16, 128), 256, 0, stream>>>(memory, wpv_h, wpv_l, bv, v_ws, 1.0f);
  attnv_kernel<<<dim3(16, 2, 16), 256, 0, stream>>>(attn, v_ws, out);
}

// Round 6
// 757.165 us; speedup vs baseline: 2.6606x; 1.1141x over previous
//
#include <hip/hip_runtime.h>
#include <math.h>

// ConvAttention on MI355X — Round 6: pre-packed bf16 hi/lo input (channel-last) feeds
// a copy-only-staging MFMA conv. Falls back to round-5 path if workspace is too small.
//
// Round-5 measured: 843.6 us, conv_mfma<3>=315 us @ MfmaUtil 23.5 / VALUBusy 24 / 1.9e7 bank conf.
// Staging (divides+converts+scalar u16 writes between barriers) is the limiter -> hoist to pack_x.
//
// Packed layout PX[s=b*18+l][pixel=y*32+x][128 shorts: ci0..63 hi | ci0..63 lo].
// Conv LDS: [4 rows][34 px][136 shorts] (pixel stride 136 -> 68 words = 4 mod 32: conflict-minimal
// for both staged ds_write_b128 and A-frag ds_read_b128).

#define B_     8
#define CIN    64
#define COUT   128
#define LDEPTH 18
#define HW2    1024
#define NH     2
#define DQ     9
#define PQ     9216
#define PV     8192

typedef __attribute__((ext_vector_type(8))) short short8;
typedef __attribute__((ext_vector_type(4))) float f32x4;

static __device__ __forceinline__ unsigned short f2bf(float f) {
  unsigned u = __float_as_uint(f);
  unsigned r = (u + 0x7fffu + ((u >> 16) & 1u)) >> 16;   // RN-even
  return (unsigned short)r;
}
static __device__ __forceinline__ float bf2f(unsigned short h) {
  return __uint_as_float(((unsigned)h) << 16);
}

// ---------------- weight repack: [co][ci][taps] fp32 -> [co][tap][ci] bf16 hi/lo ----------------
__global__ void repack_w(const float* __restrict__ src, short* __restrict__ dh,
                         short* __restrict__ dl, int taps) {
  const int idx = blockIdx.x * 256 + threadIdx.x;
  const int total = 128 * 64 * taps;
  if (idx >= total) return;
  const int ci = idx & 63;
  const int t = idx >> 6;            // co*taps + tap
  const int co = t / taps;
  const int tap = t - co * taps;
  const float v = src[(size_t)(co * 64 + ci) * taps + tap];
  const unsigned short h = f2bf(v);
  dh[idx] = (short)h;
  dl[idx] = (short)f2bf(v - bf2f(h));
}

// ---------------- input pack: NCDHW fp32 -> [s][pixel][64 hi | 64 lo] bf16 ----------------
// grid (144 slices, 4 pixel-blocks of 256), block 256. Thread: 1 pixel x 16 ci.
__global__ __launch_bounds__(256) void pack_x(const float* __restrict__ X,
                                              short* __restrict__ PX) {
  const int s = blockIdx.x;                  // b*18 + l
  const int b = s / LDEPTH, l = s - b * LDEPTH;
  const int t = threadIdx.x;
  const int px = blockIdx.y * 64 + (t >> 2);
  const int cg = t & 3;
  short hi[16], lo[16];
#pragma unroll
  for (int i = 0; i < 16; ++i) {
    const int ci = cg * 16 + i;
    const float v = X[((size_t)(b * CIN + ci) * LDEPTH + l) * HW2 + px];
    const unsigned short h = f2bf(v);
    hi[i] = (short)h;
    lo[i] = (short)f2bf(v - bf2f(h));
  }
  short* dst = PX + ((size_t)s * HW2 + px) * 128 + cg * 16;
  *(short8*)(dst)      = *(short8*)&hi[0];
  *(short8*)(dst + 8)  = *(short8*)&hi[8];
  *(short8*)(dst + 64) = *(short8*)&lo[0];
  *(short8*)(dst + 72) = *(short8*)&lo[8];
}

// ---------------- NEW conv: copy-only staging from PX ----------------
// block = 64 pos x 128 co, 4 waves (each 64 pos x 32 co). LDS pixel stride 136 shorts.
template <int KD>
__global__ __launch_bounds__(256, 4) void conv_mfma_px(
    const short* __restrict__ PX, const short* __restrict__ wh, const short* __restrict__ wl,
    const float* __restrict__ bias, float* __restrict__ out, float scale) {
  constexpr int TAPS = KD * 9;
  constexpr int OUTP = (KD == 1) ? PQ : PV;
  __shared__ __align__(16) short xs[4 * 34 * 136];
  const int tid = threadIdx.x;
  const int wave = tid >> 6;
  const int lane = tid & 63;
  const int l15 = lane & 15;
  const int l4 = lane >> 4;

  const int sB = blockIdx.y;
  int b, n, d, l_base;
  if (KD == 1) { b = sB / LDEPTH; const int l = sB - b * LDEPTH; n = (l >= DQ) ? 1 : 0; d = l - n * DQ; l_base = l; }
  else         { b = sB >> 4; const int dv = sB & 15; n = dv >> 3; d = dv & 7; l_base = dv; }
  const int p0 = blockIdx.x * 64;
  const int y0 = blockIdx.x * 2;

  f32x4 acc[2][4];
#pragma unroll
  for (int i = 0; i < 2; ++i)
#pragma unroll
    for (int j = 0; j < 4; ++j) acc[i][j] = (f32x4){0.f, 0.f, 0.f, 0.f};

  float bval[2];
  bval[0] = bias[wave * 32 + l15];
  bval[1] = bias[wave * 32 + 16 + l15];

  for (int kd = 0; kd < KD; ++kd) {
    const size_t sbase = (size_t)(b * LDEPTH + l_base + kd) * HW2;
    __syncthreads();
    // stage: 4 rows x 34 px x 16 chunks of 16B = 2176 vector copies (8.5/thread)
    for (int idx = tid; idx < 2176; idx += 256) {
      const int row = idx / 544;
      const int rem = idx - row * 544;
      const int pxx = rem >> 4;
      const int c = rem & 15;
      const int y = y0 - 1 + row;
      const int x = pxx - 1;
      short8 v = (short8){0, 0, 0, 0, 0, 0, 0, 0};
      if ((unsigned)y < 32u && (unsigned)x < 32u)
        v = *(const short8*)(PX + (sbase + y * 32 + x) * 128 + c * 8);
      *(short8*)(xs + (row * 34 + pxx) * 136 + c * 8) = v;
    }
    __syncthreads();
    for (int cc = 0; cc < 2; ++cc) {
#pragma unroll
      for (int tap = 0; tap < 9; ++tap) {
        const int ky = tap / 3, kx = tap - ky * 3;
        const int tapf = kd * 9 + tap;
        short8 bh[2], bl[2];
#pragma unroll
        for (int cf = 0; cf < 2; ++cf) {
          const size_t wofs = ((size_t)(wave * 32 + cf * 16 + l15) * TAPS + tapf) * 64 + cc * 32 + l4 * 8;
          bh[cf] = *(const short8*)(wh + wofs);
          bl[cf] = *(const short8*)(wl + wofs);
        }
        short8 ah[4], al[4];
#pragma unroll
        for (int pf = 0; pf < 4; ++pf) {
          const int base = (((pf >> 1) + ky) * 34 + (pf & 1) * 16 + kx + l15) * 136 + cc * 32 + l4 * 8;
          ah[pf] = *(const short8*)(xs + base);
          al[pf] = *(const short8*)(xs + base + 64);
        }
#pragma unroll
        for (int cf = 0; cf < 2; ++cf)
#pragma unroll
          for (int pf = 0; pf < 4; ++pf) {
            acc[cf][pf] = __builtin_amdgcn_mfma_f32_16x16x32_bf16(ah[pf], bh[cf], acc[cf][pf], 0, 0, 0);
            acc[cf][pf] = __builtin_amdgcn_mfma_f32_16x16x32_bf16(ah[pf], bl[cf], acc[cf][pf], 0, 0, 0);
            acc[cf][pf] = __builtin_amdgcn_mfma_f32_16x16x32_bf16(al[pf], bh[cf], acc[cf][pf], 0, 0, 0);
          }
      }
    }
  }

  const size_t obase = (size_t)((b * NH + n) * COUT) * OUTP + (size_t)d * HW2;
#pragma unroll
  for (int cf = 0; cf < 2; ++cf) {
    const int co = wave * 32 + cf * 16 + l15;
#pragma unroll
    for (int pf = 0; pf < 4; ++pf) {
      f32x4 r;
#pragma unroll
      for (int j = 0; j < 4; ++j) r[j] = (acc[cf][pf][j] + bval[cf]) * scale;
      const int pos = p0 + (pf >> 1) * 32 + (pf & 1) * 16 + l4 * 4;
      *(f32x4*)(out + obase + (size_t)co * OUTP + pos) = r;
    }
  }
}

// ---------------- OLD conv (round-5 fallback, known-passing) ----------------
__device__ __forceinline__ void stage_slice_old(short* xh, short* xl, const float* __restrict__ X,
                                                int b, int l, int ci0, int y0, int tid) {
  for (int idx = tid; idx < 4352; idx += 256) {
    const int ci = idx / 136;
    const int r = idx - ci * 136;
    const int row = r / 34;
    const int px = r - row * 34;
    const int y = y0 - 1 + row;
    const int x = px - 1;
    float v = 0.f;
    if (y >= 0 && y < 32 && (unsigned)x < 32u)
      v = X[((size_t)(b * CIN + ci0 + ci) * LDEPTH + l) * HW2 + y * 32 + x];
    const unsigned short h = f2bf(v);
    const int cell = row * 34 + px;
    xh[cell * 40 + ci] = (short)h;
    xl[cell * 40 + ci] = (short)f2bf(v - bf2f(h));
  }
}

template <int KD>
__global__ __launch_bounds__(256, 2) void conv_mfma(
    const float* __restrict__ X, const short* __restrict__ wh, const short* __restrict__ wl,
    const float* __restrict__ bias, float* __restrict__ out, float scale) {
  constexpr int TAPS = KD * 9;
  constexpr int OUTP = (KD == 1) ? PQ : PV;
  __shared__ __align__(16) short xh[4 * 34 * 40];
  __shared__ __align__(16) short xl[4 * 34 * 40];
  const int tid = threadIdx.x;
  const int wave = tid >> 6;
  const int lane = tid & 63;
  const int l15 = lane & 15;
  const int l4 = lane >> 4;

  const int s = blockIdx.y;
  int b, n, d, l_base;
  if (KD == 1) { b = s / LDEPTH; const int l = s - b * LDEPTH; n = (l >= DQ) ? 1 : 0; d = l - n * DQ; l_base = l; }
  else         { b = s >> 4; const int dv = s & 15; n = dv >> 3; d = dv & 7; l_base = dv; }
  const int p0 = blockIdx.x * 64;
  const int y0 = blockIdx.x * 2;

  f32x4 acc[2][4];
#pragma unroll
  for (int i = 0; i < 2; ++i)
#pragma unroll
    for (int j = 0; j < 4; ++j) acc[i][j] = (f32x4){0.f, 0.f, 0.f, 0.f};

  float bval[2];
  bval[0] = bias[wave * 32 + l15];
  bval[1] = bias[wave * 32 + 16 + l15];

  const short* ah_base = xh + l15 * 40 + l4 * 8;
  const short* al_base = xl + l15 * 40 + l4 * 8;

  for (int kd = 0; kd < KD; ++kd) {
    for (int cc = 0; cc < 2; ++cc) {
      __syncthreads();
      stage_slice_old(xh, xl, X, b, l_base + kd, cc * 32, y0, tid);
      __syncthreads();
#pragma unroll
      for (int tap = 0; tap < 9; ++tap) {
        const int ky = tap / 3, kx = tap % 3;
        const int tapf = kd * 9 + tap;
        short8 bh[2], bl[2];
#pragma unroll
        for (int cf = 0; cf < 2; ++cf) {
          const size_t wofs = ((size_t)(wave * 32 + cf * 16 + l15) * TAPS + tapf) * 64 + cc * 32 + l4 * 8;
          bh[cf] = *(const short8*)(wh + wofs);
          bl[cf] = *(const short8*)(wl + wofs);
        }
        short8 ah[4], al[4];
#pragma unroll
        for (int pf = 0; pf < 4; ++pf) {
          const int off = (((pf >> 1) + ky) * 34 + (pf & 1) * 16 + kx) * 40;
          ah[pf] = *(const short8*)(ah_base + off);
          al[pf] = *(const short8*)(al_base + off);
        }
#pragma unroll
        for (int cf = 0; cf < 2; ++cf)
#pragma unroll
          for (int pf = 0; pf < 4; ++pf) {
            acc[cf][pf] = __builtin_amdgcn_mfma_f32_16x16x32_bf16(ah[pf], bh[cf], acc[cf][pf], 0, 0, 0);
            acc[cf][pf] = __builtin_amdgcn_mfma_f32_16x16x32_bf16(ah[pf], bl[cf], acc[cf][pf], 0, 0, 0);
            acc[cf][pf] = __builtin_amdgcn_mfma_f32_16x16x32_bf16(al[pf], bh[cf], acc[cf][pf], 0, 0, 0);
          }
      }
    }
  }

  const size_t obase = (size_t)((b * NH + n) * COUT) * OUTP + (size_t)d * HW2;
#pragma unroll
  for (int cf = 0; cf < 2; ++cf) {
    const int co = wave * 32 + cf * 16 + l15;
#pragma unroll
    for (int pf = 0; pf < 4; ++pf) {
      f32x4 r;
#pragma unroll
      for (int j = 0; j < 4; ++j) r[j] = (acc[cf][pf][j] + bval[cf]) * scale;
      const int pos = p0 + (pf >> 1) * 32 + (pf & 1) * 16 + l4 * 4;
      *(f32x4*)(out + obase + (size_t)co * OUTP + pos) = r;
    }
  }
}

// ---------------- logits: split-K GEMM 128x128 over K=9216 (unchanged) ----------------
__global__ __launch_bounds__(256, 2) void logit_kernel(
    const float* __restrict__ Qg, const float* __restrict__ Kg,
    float* __restrict__ part) {
  __shared__ float Qs[16][128];
  __shared__ float Ks[16][128];
  const int ks = blockIdx.x;
  const int bn = blockIdx.y;
  const float* Q = Qg + (size_t)bn * COUT * PQ;
  const float* K = Kg + (size_t)bn * COUT * PQ;
  const int tid = threadIdx.x;
  const int tc = tid >> 4;
  const int tm = tid & 15;
  float acc[8][8];
#pragma unroll
  for (int i = 0; i < 8; ++i)
#pragma unroll
    for (int j = 0; j < 8; ++j) acc[i][j] = 0.f;

  const int kbase = ks * 576;
  for (int kt = 0; kt < 36; ++kt) {
    const int k0 = kbase + kt * 16;
    __syncthreads();
#pragma unroll
    for (int i = 0; i < 2; ++i) {
      const int fid = tid + 256 * i;
      const int c = fid >> 2;
      const int kq = fid & 3;
      const float4 qa = *(const float4*)(Q + (size_t)c * PQ + k0 + kq * 4);
      const float4 ka = *(const float4*)(K + (size_t)c * PQ + k0 + kq * 4);
      Qs[kq * 4 + 0][c] = qa.x; Qs[kq * 4 + 1][c] = qa.y;
      Qs[kq * 4 + 2][c] = qa.z; Qs[kq * 4 + 3][c] = qa.w;
      Ks[kq * 4 + 0][c] = ka.x; Ks[kq * 4 + 1][c] = ka.y;
      Ks[kq * 4 + 2][c] = ka.z; Ks[kq * 4 + 3][c] = ka.w;
    }
    __syncthreads();
#pragma unroll
    for (int kk = 0; kk < 16; ++kk) {
      float a[8], bv[8];
      *(float4*)&a[0] = *(const float4*)&Qs[kk][tc * 8];
      *(float4*)&a[4] = *(const float4*)&Qs[kk][tc * 8 + 4];
#pragma unroll
      for (int j = 0; j < 8; ++j) bv[j] = Ks[kk][tm + 16 * j];
#pragma unroll
      for (int i = 0; i < 8; ++i)
#pragma unroll
        for (int j = 0; j < 8; ++j)
          acc[i][j] = fmaf(a[i], bv[j], acc[i][j]);
    }
  }
  float* pp = part + ((size_t)(bn * 16 + ks) << 14);
#pragma unroll
  for (int i = 0; i < 8; ++i)
#pragma unroll
    for (int j = 0; j < 8; ++j)
      pp[(tc * 8 + i) * 128 + tm + 16 * j] = acc[i][j];
}

// ---------------- reduce partials + row softmax (unchanged) ----------------
__global__ void softmax_kernel(const float* __restrict__ part, float* __restrict__ attn) {
  const int row = blockIdx.x;
  const int bn = row >> 7;
  const int c = row & 127;
  const int lane = threadIdx.x;
  float v0 = 0.f, v1 = 0.f;
  for (int ks = 0; ks < 16; ++ks) {
    const float* pp = part + ((size_t)(bn * 16 + ks) << 14) + c * 128;
    v0 += pp[lane];
    v1 += pp[lane + 64];
  }
  float mx = fmaxf(v0, v1);
#pragma unroll
  for (int off = 32; off > 0; off >>= 1) mx = fmaxf(mx, __shfl_xor(mx, off));
  const float e0 = expf(v0 - mx);
  const float e1 = expf(v1 - mx);
  float sum = e0 + e1;
#pragma unroll
  for (int off = 32; off > 0; off >>= 1) sum += __shfl_xor(sum, off);
  const float inv = 1.f / sum;
  float* rp = attn + ((size_t)bn << 14) + c * 128;
  rp[lane] = e0 * inv;
  rp[lane + 64] = e1 * inv;
}

// ---------------- out = attn @ v, packed to (B,C,16,H,W) (unchanged) ----------------
__global__ __launch_bounds__(256, 2) void attnv_kernel(
    const float* __restrict__ attn, const float* __restrict__ Vg,
    float* __restrict__ out) {
  __shared__ float As[16][64];
  __shared__ float Vs[16][512];
  const int bn = blockIdx.z;
  const int b = bn >> 1, n = bn & 1;
  const int c0 = blockIdx.y * 64;
  const int p0 = blockIdx.x * 512;
  const int tid = threadIdx.x;
  const int tc = tid >> 5;
  const int tp = tid & 31;
  const float* V = Vg + (size_t)bn * COUT * PV;
  const float* A = attn + ((size_t)bn << 14);
  float acc[8][16];
#pragma unroll
  for (int i = 0; i < 8; ++i)
#pragma unroll
    for (int j = 0; j < 16; ++j) acc[i][j] = 0.f;

  for (int mt = 0; mt < 8; ++mt) {
    const int m0 = mt * 16;
    __syncthreads();
    {
      const int cc = tid >> 2, mq = tid & 3;
      const float4 aa = *(const float4*)(A + (size_t)(c0 + cc) * 128 + m0 + mq * 4);
      As[mq * 4 + 0][cc] = aa.x; As[mq * 4 + 1][cc] = aa.y;
      As[mq * 4 + 2][cc] = aa.z; As[mq * 4 + 3][cc] = aa.w;
#pragma unroll
      for (int i = 0; i < 8; ++i) {
        const int fid = tid + 256 * i;
        const int mm = fid >> 7, pq = fid & 127;
        const float4 vv = *(const float4*)(V + (size_t)(m0 + mm) * PV + p0 + pq * 4);
        *(float4*)&Vs[mm][pq * 4] = vv;
      }
    }
    __syncthreads();
#pragma unroll
    for (int mm = 0; mm < 16; ++mm) {
      float a[8];
      *(float4*)&a[0] = *(const float4*)&As[mm][tc * 8];
      *(float4*)&a[4] = *(const float4*)&As[mm][tc * 8 + 4];
#pragma unroll
      for (int j = 0; j < 16; ++j) {
        const float vv = Vs[mm][tp + 32 * j];
#pragma unroll
        for (int i = 0; i < 8; ++i)
          acc[i][j] = fmaf(a[i], vv, acc[i][j]);
      }
    }
  }
#pragma unroll
  for (int i = 0; i < 8; ++i) {
    const size_t ob = ((size_t)(b * COUT + c0 + tc * 8 + i) << 14) + ((size_t)n << 13) + p0 + tp;
#pragma unroll
    for (int j = 0; j < 16; ++j)
      out[ob + 32 * j] = acc[i][j];
  }
}

extern "C" void kernel_launch(void* const* d_in, const int* in_sizes, int n_in,
                              void* d_out, int out_size, void* d_ws, size_t ws_size,
                              hipStream_t stream) {
  const float* input  = (const float*)d_in[0];
  const float* memory = (const float*)d_in[1];
  const float* wq = (const float*)d_in[2];
  const float* bq = (const float*)d_in[3];
  const float* wk = (const float*)d_in[4];
  const float* bk = (const float*)d_in[5];
  const float* wv = (const float*)d_in[6];
  const float* bv = (const float*)d_in[7];
  float* out = (float*)d_out;

  const size_t QK_ELEMS = (size_t)16 * COUT * PQ;      // 18,874,368 floats (72 MiB)
  const size_t PX_SHORTS = (size_t)144 * HW2 * 128;    // 18,874,368 shorts (36 MiB)
  const size_t PART_ELEMS = (size_t)256 << 14;         // 4,194,304 floats
  const size_t ATTN_ELEMS = (size_t)16 << 14;          // 262,144 floats
  const size_t NEED_OLD = (2 * QK_ELEMS + PART_ELEMS + ATTN_ELEMS) * 4;
  const size_t NEED_NEW = NEED_OLD + PX_SHORTS * 2;

  if (ws_size >= NEED_NEW) {
    // ---- new path: PX-packed staging ----
    short* px_buf = (short*)d_ws;
    float* q_ws = (float*)(px_buf + PX_SHORTS);
    float* k_ws = q_ws + QK_ELEMS;
    float* part = k_ws + QK_ELEMS;
    float* attn = part + PART_ELEMS;
    float* v_ws = q_ws;

    short* wpq_h = (short*)part;
    short* wpq_l = wpq_h + 128 * 9 * 64;
    short* wpk_h = wpq_l + 128 * 9 * 64;
    short* wpk_l = wpk_h + 128 * 9 * 64;
    short* wpv_h = (short*)(q_ws + (size_t)16 * COUT * PV);
    short* wpv_l = wpv_h + 128 * 27 * 64;

    repack_w<<<288, 256, 0, stream>>>(wq, wpq_h, wpq_l, 9);
    repack_w<<<288, 256, 0, stream>>>(wk, wpk_h, wpk_l, 9);
    pack_x<<<dim3(144, 16), 256, 0, stream>>>(input, px_buf);
    conv_mfma_px<1><<<dim3(16, 144), 256, 0, stream>>>(px_buf, wpq_h, wpq_l, bq, q_ws, 0.5f);
    pack_x<<<dim3(144, 16), 256, 0, stream>>>(memory, px_buf);   // stream-serialized after conv q
    conv_mfma_px<1><<<dim3(16, 144), 256, 0, stream>>>(px_buf, wpk_h, wpk_l, bk, k_ws, 1.0f);
    logit_kernel<<<dim3(16, 16), 256, 0, stream>>>(q_ws, k_ws, part);
    softmax_kernel<<<2048, 64, 0, stream>>>(part, attn);
    repack_w<<<864, 256, 0, stream>>>(wv, wpv_h, wpv_l, 27);
    conv_mfma_px<3><<<dim3(16, 128), 256, 0, stream>>>(px_buf, wpv_h, wpv_l, bv, v_ws, 1.0f);
    attnv_kernel<<<dim3(16, 2, 16), 256, 0, stream>>>(attn, v_ws, out);
    return;
  }
  if (ws_size < NEED_OLD) return;  // clean validation failure, not a crash

  // ---- fallback: round-5 known-passing path ----
  float* q_ws = (float*)d_ws;
  float* k_ws = q_ws + QK_ELEMS;
  float* part = k_ws + QK_ELEMS;
  float* attn = part + PART_ELEMS;
  float* v_ws = q_ws;

  short* wpq_h = (short*)part;
  short* wpq_l = wpq_h + 128 * 9 * 64;
  short* wpk_h = wpq_l + 128 * 9 * 64;
  short* wpk_l = wpk_h + 128 * 9 * 64;
  short* wpv_h = (short*)(q_ws + (size_t)16 * COUT * PV);
  short* wpv_l = wpv_h + 128 * 27 * 64;

  repack_w<<<288, 256, 0, stream>>>(wq, wpq_h, wpq_l, 9);
  repack_w<<<288, 256, 0, stream>>>(wk, wpk_h, wpk_l, 9);
  conv_mfma<1><<<dim3(16, 144), 256, 0, stream>>>(input,  wpq_h, wpq_l, bq, q_ws, 0.5f);
  conv_mfma<1><<<dim3(16, 144), 256, 0, stream>>>(memory, wpk_h, wpk_l, bk, k_ws, 1.0f);
  logit_kernel<<<dim3(16, 16), 256, 0, stream>>>(q_ws, k_ws, part);
  softmax_kernel<<<2048, 64, 0, stream>>>(part, attn);
  repack_w<<<864, 256, 0, stream>>>(wv, wpv_h, wpv_l, 27);
  conv_mfma<3><<<dim3(16, 128), 256, 0, stream>>>(memory, wpv_h, wpv_l, bv, v_ws, 1.0f);
  attnv_kernel<<<dim3(16, 2, 16), 256, 0, stream>>>(attn, v_ws, out);
}

// Round 7
// 607.805 us; speedup vs baseline: 3.3144x; 1.2457x over previous
//
#include <hip/hip_runtime.h>
#include <math.h>

// ConvAttention on MI355X — Round 7: 128 positions/block conv (halve weight L2 traffic).
// Round-6 measured: 757 us; conv_mfma_px<3>=268 us @ MfmaUtil 27.7 / VALU 11 / Occ 44.
// Weight re-fetch per 64-pos tile put L2 demand (~70 B/cy/CU) over the ~56 B/cy/CU ceiling.
// This round: pf=8 (128 pos/block), 6-row halo LDS @ pixel stride 140 shorts (bank-spread),
// grid x halves. pack/logit/softmax/attnv unchanged.

#define B_     8
#define CIN    64
#define COUT   128
#define LDEPTH 18
#define HW2    1024
#define NH     2
#define DQ     9
#define PQ     9216
#define PV     8192
#define XSTR   140   // LDS pixel stride in shorts: 70 words == 6 mod 32 -> distinct bank starts

typedef __attribute__((ext_vector_type(8))) short short8;
typedef __attribute__((ext_vector_type(4))) float f32x4;

static __device__ __forceinline__ unsigned short f2bf(float f) {
  unsigned u = __float_as_uint(f);
  unsigned r = (u + 0x7fffu + ((u >> 16) & 1u)) >> 16;   // RN-even
  return (unsigned short)r;
}
static __device__ __forceinline__ float bf2f(unsigned short h) {
  return __uint_as_float(((unsigned)h) << 16);
}

// ---------------- weight repack: [co][ci][taps] fp32 -> [co][tap][ci] bf16 hi/lo ----------------
__global__ void repack_w(const float* __restrict__ src, short* __restrict__ dh,
                         short* __restrict__ dl, int taps) {
  const int idx = blockIdx.x * 256 + threadIdx.x;
  const int total = 128 * 64 * taps;
  if (idx >= total) return;
  const int ci = idx & 63;
  const int t = idx >> 6;            // co*taps + tap
  const int co = t / taps;
  const int tap = t - co * taps;
  const float v = src[(size_t)(co * 64 + ci) * taps + tap];
  const unsigned short h = f2bf(v);
  dh[idx] = (short)h;
  dl[idx] = (short)f2bf(v - bf2f(h));
}

// ---------------- input pack: NCDHW fp32 -> [s][pixel][64 hi | 64 lo] bf16 ----------------
__global__ __launch_bounds__(256) void pack_x(const float* __restrict__ X,
                                              short* __restrict__ PX) {
  const int s = blockIdx.x;                  // b*18 + l
  const int b = s / LDEPTH, l = s - b * LDEPTH;
  const int t = threadIdx.x;
  const int px = blockIdx.y * 64 + (t >> 2);
  const int cg = t & 3;
  short hi[16], lo[16];
#pragma unroll
  for (int i = 0; i < 16; ++i) {
    const int ci = cg * 16 + i;
    const float v = X[((size_t)(b * CIN + ci) * LDEPTH + l) * HW2 + px];
    const unsigned short h = f2bf(v);
    hi[i] = (short)h;
    lo[i] = (short)f2bf(v - bf2f(h));
  }
  short* dst = PX + ((size_t)s * HW2 + px) * 128 + cg * 16;
  *(short8*)(dst)      = *(short8*)&hi[0];
  *(short8*)(dst + 8)  = *(short8*)&hi[8];
  *(short8*)(dst + 64) = *(short8*)&lo[0];
  *(short8*)(dst + 72) = *(short8*)&lo[8];
}

// ---------------- conv: block = 128 pos x 128 co, 4 waves (each 128 pos x 32 co) ----------------
template <int KD>
__global__ __launch_bounds__(256, 2) void conv_mfma_px(
    const short* __restrict__ PX, const short* __restrict__ wh, const short* __restrict__ wl,
    const float* __restrict__ bias, float* __restrict__ out, float scale) {
  constexpr int TAPS = KD * 9;
  constexpr int OUTP = (KD == 1) ? PQ : PV;
  __shared__ __align__(16) short xs[6 * 34 * XSTR];   // 57.1 KB
  const int tid = threadIdx.x;
  const int wave = tid >> 6;
  const int lane = tid & 63;
  const int l15 = lane & 15;
  const int l4 = lane >> 4;

  const int sB = blockIdx.y;
  int b, n, d, l_base;
  if (KD == 1) { b = sB / LDEPTH; const int l = sB - b * LDEPTH; n = (l >= DQ) ? 1 : 0; d = l - n * DQ; l_base = l; }
  else         { b = sB >> 4; const int dv = sB & 15; n = dv >> 3; d = dv & 7; l_base = dv; }
  const int p0 = blockIdx.x * 128;
  const int y0 = blockIdx.x * 4;

  f32x4 acc[2][8];
#pragma unroll
  for (int i = 0; i < 2; ++i)
#pragma unroll
    for (int j = 0; j < 8; ++j) acc[i][j] = (f32x4){0.f, 0.f, 0.f, 0.f};

  float bval[2];
  bval[0] = bias[wave * 32 + l15];
  bval[1] = bias[wave * 32 + 16 + l15];

  for (int kd = 0; kd < KD; ++kd) {
    const size_t sbase = (size_t)(b * LDEPTH + l_base + kd) * HW2;
    __syncthreads();
    // stage 6 halo rows x 34 px x 16 chunks of 16B = 3264 vector copies (12.75/thread)
    for (int idx = tid; idx < 3264; idx += 256) {
      const int row = idx / 544;
      const int rem = idx - row * 544;
      const int pxx = rem >> 4;
      const int c = rem & 15;
      const int y = y0 - 1 + row;
      const int x = pxx - 1;
      short8 v = (short8){0, 0, 0, 0, 0, 0, 0, 0};
      if ((unsigned)y < 32u && (unsigned)x < 32u)
        v = *(const short8*)(PX + (sbase + y * 32 + x) * 128 + c * 8);
      *(short8*)(xs + (row * 34 + pxx) * XSTR + c * 8) = v;
    }
    __syncthreads();
    for (int cc = 0; cc < 2; ++cc) {
#pragma unroll
      for (int tap = 0; tap < 9; ++tap) {
        const int ky = tap / 3, kx = tap - ky * 3;
        const int tapf = kd * 9 + tap;
        short8 bh[2], bl[2];
#pragma unroll
        for (int cf = 0; cf < 2; ++cf) {
          const size_t wofs = ((size_t)(wave * 32 + cf * 16 + l15) * TAPS + tapf) * 64 + cc * 32 + l4 * 8;
          bh[cf] = *(const short8*)(wh + wofs);
          bl[cf] = *(const short8*)(wl + wofs);
        }
        short8 ah[8], al[8];
#pragma unroll
        for (int pf = 0; pf < 8; ++pf) {
          const int base = (((pf >> 1) + ky) * 34 + (pf & 1) * 16 + kx + l15) * XSTR + cc * 32 + l4 * 8;
          ah[pf] = *(const short8*)(xs + base);
          al[pf] = *(const short8*)(xs + base + 64);
        }
#pragma unroll
        for (int cf = 0; cf < 2; ++cf)
#pragma unroll
          for (int pf = 0; pf < 8; ++pf) {
            acc[cf][pf] = __builtin_amdgcn_mfma_f32_16x16x32_bf16(ah[pf], bh[cf], acc[cf][pf], 0, 0, 0);
            acc[cf][pf] = __builtin_amdgcn_mfma_f32_16x16x32_bf16(ah[pf], bl[cf], acc[cf][pf], 0, 0, 0);
            acc[cf][pf] = __builtin_amdgcn_mfma_f32_16x16x32_bf16(al[pf], bh[cf], acc[cf][pf], 0, 0, 0);
          }
      }
    }
  }

  const size_t obase = (size_t)((b * NH + n) * COUT) * OUTP + (size_t)d * HW2;
#pragma unroll
  for (int cf = 0; cf < 2; ++cf) {
    const int co = wave * 32 + cf * 16 + l15;
#pragma unroll
    for (int pf = 0; pf < 8; ++pf) {
      f32x4 r;
#pragma unroll
      for (int j = 0; j < 4; ++j) r[j] = (acc[cf][pf][j] + bval[cf]) * scale;
      const int pos = p0 + (pf >> 1) * 32 + (pf & 1) * 16 + l4 * 4;
      *(f32x4*)(out + obase + (size_t)co * OUTP + pos) = r;
    }
  }
}

// ---------------- logits: split-K GEMM 128x128 over K=9216 (unchanged) ----------------
__global__ __launch_bounds__(256, 2) void logit_kernel(
    const float* __restrict__ Qg, const float* __restrict__ Kg,
    float* __restrict__ part) {
  __shared__ float Qs[16][128];
  __shared__ float Ks[16][128];
  const int ks = blockIdx.x;
  const int bn = blockIdx.y;
  const float* Q = Qg + (size_t)bn * COUT * PQ;
  const float* K = Kg + (size_t)bn * COUT * PQ;
  const int tid = threadIdx.x;
  const int tc = tid >> 4;
  const int tm = tid & 15;
  float acc[8][8];
#pragma unroll
  for (int i = 0; i < 8; ++i)
#pragma unroll
    for (int j = 0; j < 8; ++j) acc[i][j] = 0.f;

  const int kbase = ks * 576;
  for (int kt = 0; kt < 36; ++kt) {
    const int k0 = kbase + kt * 16;
    __syncthreads();
#pragma unroll
    for (int i = 0; i < 2; ++i) {
      const int fid = tid + 256 * i;
      const int c = fid >> 2;
      const int kq = fid & 3;
      const float4 qa = *(const float4*)(Q + (size_t)c * PQ + k0 + kq * 4);
      const float4 ka = *(const float4*)(K + (size_t)c * PQ + k0 + kq * 4);
      Qs[kq * 4 + 0][c] = qa.x; Qs[kq * 4 + 1][c] = qa.y;
      Qs[kq * 4 + 2][c] = qa.z; Qs[kq * 4 + 3][c] = qa.w;
      Ks[kq * 4 + 0][c] = ka.x; Ks[kq * 4 + 1][c] = ka.y;
      Ks[kq * 4 + 2][c] = ka.z; Ks[kq * 4 + 3][c] = ka.w;
    }
    __syncthreads();
#pragma unroll
    for (int kk = 0; kk < 16; ++kk) {
      float a[8], bv[8];
      *(float4*)&a[0] = *(const float4*)&Qs[kk][tc * 8];
      *(float4*)&a[4] = *(const float4*)&Qs[kk][tc * 8 + 4];
#pragma unroll
      for (int j = 0; j < 8; ++j) bv[j] = Ks[kk][tm + 16 * j];
#pragma unroll
      for (int i = 0; i < 8; ++i)
#pragma unroll
        for (int j = 0; j < 8; ++j)
          acc[i][j] = fmaf(a[i], bv[j], acc[i][j]);
    }
  }
  float* pp = part + ((size_t)(bn * 16 + ks) << 14);
#pragma unroll
  for (int i = 0; i < 8; ++i)
#pragma unroll
    for (int j = 0; j < 8; ++j)
      pp[(tc * 8 + i) * 128 + tm + 16 * j] = acc[i][j];
}

// ---------------- reduce partials + row softmax (unchanged) ----------------
__global__ void softmax_kernel(const float* __restrict__ part, float* __restrict__ attn) {
  const int row = blockIdx.x;
  const int bn = row >> 7;
  const int c = row & 127;
  const int lane = threadIdx.x;
  float v0 = 0.f, v1 = 0.f;
  for (int ks = 0; ks < 16; ++ks) {
    const float* pp = part + ((size_t)(bn * 16 + ks) << 14) + c * 128;
    v0 += pp[lane];
    v1 += pp[lane + 64];
  }
  float mx = fmaxf(v0, v1);
#pragma unroll
  for (int off = 32; off > 0; off >>= 1) mx = fmaxf(mx, __shfl_xor(mx, off));
  const float e0 = expf(v0 - mx);
  const float e1 = expf(v1 - mx);
  float sum = e0 + e1;
#pragma unroll
  for (int off = 32; off > 0; off >>= 1) sum += __shfl_xor(sum, off);
  const float inv = 1.f / sum;
  float* rp = attn + ((size_t)bn << 14) + c * 128;
  rp[lane] = e0 * inv;
  rp[lane + 64] = e1 * inv;
}

// ---------------- out = attn @ v, packed to (B,C,16,H,W) (unchanged) ----------------
__global__ __launch_bounds__(256, 2) void attnv_kernel(
    const float* __restrict__ attn, const float* __restrict__ Vg,
    float* __restrict__ out) {
  __shared__ float As[16][64];
  __shared__ float Vs[16][512];
  const int bn = blockIdx.z;
  const int b = bn >> 1, n = bn & 1;
  const int c0 = blockIdx.y * 64;
  const int p0 = blockIdx.x * 512;
  const int tid = threadIdx.x;
  const int tc = tid >> 5;
  const int tp = tid & 31;
  const float* V = Vg + (size_t)bn * COUT * PV;
  const float* A = attn + ((size_t)bn << 14);
  float acc[8][16];
#pragma unroll
  for (int i = 0; i < 8; ++i)
#pragma unroll
    for (int j = 0; j < 16; ++j) acc[i][j] = 0.f;

  for (int mt = 0; mt < 8; ++mt) {
    const int m0 = mt * 16;
    __syncthreads();
    {
      const int cc = tid >> 2, mq = tid & 3;
      const float4 aa = *(const float4*)(A + (size_t)(c0 + cc) * 128 + m0 + mq * 4);
      As[mq * 4 + 0][cc] = aa.x; As[mq * 4 + 1][cc] = aa.y;
      As[mq * 4 + 2][cc] = aa.z; As[mq * 4 + 3][cc] = aa.w;
#pragma unroll
      for (int i = 0; i < 8; ++i) {
        const int fid = tid + 256 * i;
        const int mm = fid >> 7, pq = fid & 127;
        const float4 vv = *(const float4*)(V + (size_t)(m0 + mm) * PV + p0 + pq * 4);
        *(float4*)&Vs[mm][pq * 4] = vv;
      }
    }
    __syncthreads();
#pragma unroll
    for (int mm = 0; mm < 16; ++mm) {
      float a[8];
      *(float4*)&a[0] = *(const float4*)&As[mm][tc * 8];
      *(float4*)&a[4] = *(const float4*)&As[mm][tc * 8 + 4];
#pragma unroll
      for (int j = 0; j < 16; ++j) {
        const float vv = Vs[mm][tp + 32 * j];
#pragma unroll
        for (int i = 0; i < 8; ++i)
          acc[i][j] = fmaf(a[i], vv, acc[i][j]);
      }
    }
  }
#pragma unroll
  for (int i = 0; i < 8; ++i) {
    const size_t ob = ((size_t)(b * COUT + c0 + tc * 8 + i) << 14) + ((size_t)n << 13) + p0 + tp;
#pragma unroll
    for (int j = 0; j < 16; ++j)
      out[ob + 32 * j] = acc[i][j];
  }
}

extern "C" void kernel_launch(void* const* d_in, const int* in_sizes, int n_in,
                              void* d_out, int out_size, void* d_ws, size_t ws_size,
                              hipStream_t stream) {
  const float* input  = (const float*)d_in[0];
  const float* memory = (const float*)d_in[1];
  const float* wq = (const float*)d_in[2];
  const float* bq = (const float*)d_in[3];
  const float* wk = (const float*)d_in[4];
  const float* bk = (const float*)d_in[5];
  const float* wv = (const float*)d_in[6];
  const float* bv = (const float*)d_in[7];
  float* out = (float*)d_out;

  const size_t QK_ELEMS = (size_t)16 * COUT * PQ;      // 18,874,368 floats (72 MiB)
  const size_t PX_SHORTS = (size_t)144 * HW2 * 128;    // 18,874,368 shorts (36 MiB)
  const size_t PART_ELEMS = (size_t)256 << 14;         // 4,194,304 floats
  const size_t ATTN_ELEMS = (size_t)16 << 14;          // 262,144 floats
  const size_t NEED = (2 * QK_ELEMS + PART_ELEMS + ATTN_ELEMS) * 4 + PX_SHORTS * 2;
  if (ws_size < NEED) return;  // clean validation failure, not a crash

  short* px_buf = (short*)d_ws;
  float* q_ws = (float*)(px_buf + PX_SHORTS);
  float* k_ws = q_ws + QK_ELEMS;
  float* part = k_ws + QK_ELEMS;
  float* attn = part + PART_ELEMS;
  float* v_ws = q_ws;                                  // q region reused for v after logits

  short* wpq_h = (short*)part;                         // dead until logit
  short* wpq_l = wpq_h + 128 * 9 * 64;
  short* wpk_h = wpq_l + 128 * 9 * 64;
  short* wpk_l = wpk_h + 128 * 9 * 64;
  short* wpv_h = (short*)(q_ws + (size_t)16 * COUT * PV);  // q-tail, dead after logit
  short* wpv_l = wpv_h + 128 * 27 * 64;

  repack_w<<<288, 256, 0, stream>>>(wq, wpq_h, wpq_l, 9);
  repack_w<<<288, 256, 0, stream>>>(wk, wpk_h, wpk_l, 9);
  pack_x<<<dim3(144, 16), 256, 0, stream>>>(input, px_buf);
  conv_mfma_px<1><<<dim3(8, 144), 256, 0, stream>>>(px_buf, wpq_h, wpq_l, bq, q_ws, 0.5f);
  pack_x<<<dim3(144, 16), 256, 0, stream>>>(memory, px_buf);   // stream-serialized after conv q
  conv_mfma_px<1><<<dim3(8, 144), 256, 0, stream>>>(px_buf, wpk_h, wpk_l, bk, k_ws, 1.0f);
  logit_kernel<<<dim3(16, 16), 256, 0, stream>>>(q_ws, k_ws, part);
  softmax_kernel<<<2048, 64, 0, stream>>>(part, attn);
  repack_w<<<864, 256, 0, stream>>>(wv, wpv_h, wpv_l, 27);
  conv_mfma_px<3><<<dim3(8, 128), 256, 0, stream>>>(px_buf, wpv_h, wpv_l, bv, v_ws, 1.0f);
  attnv_kernel<<<dim3(16, 2, 16), 256, 0, stream>>>(attn, v_ws, out);
}